// Round 1
// baseline (602.819 us; speedup 1.0000x reference)
//
#include <hip/hip_runtime.h>
#include <stdint.h>

// Problem constants (fixed by reference setup_inputs)
#define TOKENS 4096
#define HIDDEN 4096   // K
#define NQ     4096
#define NKV    1024
#define NTOT   6144   // NQ + 2*NKV
#define KPACK  512    // HIDDEN / 8
#define MAXTILES 36   // max sum_d ceil(cnt_d/128)

typedef __attribute__((ext_vector_type(8))) __bf16 bf16x8;
typedef __attribute__((ext_vector_type(8))) short short8v;
typedef __attribute__((ext_vector_type(4))) float floatx4;

// fp32 -> bf16 round-to-nearest-even (finite inputs only)
__device__ __forceinline__ short f2bf(float f) {
  union { float f; unsigned u; } v; v.f = f;
  unsigned r = v.u + 0x7fffu + ((v.u >> 16) & 1u);
  return (short)(r >> 16);
}

// async global->LDS, 16B per lane; LDS dest = wave-uniform base + lane*16
__device__ __forceinline__ void load_lds16(const void* g, void* l) {
  __builtin_amdgcn_global_load_lds((__attribute__((address_space(1))) void*)(g),
                                   (__attribute__((address_space(3))) void*)(l),
                                   16, 0, 0);
}

// ---------------------------------------------------------------------------
// Kernel 1: bucket tokens by delta index + build compact tile table.
// grp[0..3]=start, grp[4..7]=count, grp[8]=n_tiles, grp[9..9+nt)=d|(rt<<2).
// ---------------------------------------------------------------------------
__global__ __launch_bounds__(256) void prep_tokens(const int* __restrict__ idx,
                                                   int* __restrict__ token_list,
                                                   int* __restrict__ grp) {
  __shared__ int cnt[4], cur[4];
  const int tid = threadIdx.x;
  if (tid < 4) cnt[tid] = 0;
  __syncthreads();
  for (int t = tid; t < TOKENS; t += 256) {
    int d = idx[t];
    if ((unsigned)d < 4u) atomicAdd(&cnt[d], 1);
  }
  __syncthreads();
  if (tid == 0) {
    int s = 0, nt = 0;
    for (int d = 0; d < 4; d++) {
      cur[d] = s; grp[d] = s; grp[4 + d] = cnt[d]; s += cnt[d];
      int tiles = (cnt[d] + 127) >> 7;
      for (int rt = 0; rt < tiles; rt++) grp[9 + nt++] = d | (rt << 2);
    }
    grp[8] = nt;
  }
  __syncthreads();
  for (int t = tid; t < TOKENS; t += 256) {
    int d = idx[t];
    if ((unsigned)d < 4u) {
      int p = atomicAdd(&cur[d], 1);
      token_list[p] = t;
    }
  }
}

// ---------------------------------------------------------------------------
// Kernel 2: x fp32 -> bf16 (row-major (TOKENS, HIDDEN)); 8 elems/thread.
// ---------------------------------------------------------------------------
__global__ __launch_bounds__(256) void cvt_x(const float* __restrict__ x,
                                             short* __restrict__ xb) {
  size_t g = (size_t)blockIdx.x * 256 + threadIdx.x;
  size_t i = g * 8;
  float4 a = ((const float4*)(x + i))[0];
  float4 b = ((const float4*)(x + i))[1];
  short8v o;
  o[0] = f2bf(a.x); o[1] = f2bf(a.y); o[2] = f2bf(a.z); o[3] = f2bf(a.w);
  o[4] = f2bf(b.x); o[5] = f2bf(b.y); o[6] = f2bf(b.z); o[7] = f2bf(b.w);
  *(short8v*)(xb + i) = o;
}

// ---------------------------------------------------------------------------
// Kernel 3: Wc[d] (NTOT x HIDDEN bf16, B^T layout) = base + dequant(delta_d).
// Transpose raw int32s through LDS: ldsq[d][kp][n], stride 72 ints.
//  phase A write  (lane->n, fixed kp): bank (8*kp + n)%32 -> 2 lanes/bank, free
//  phase B read   (lane->(kp=t&7, n=t>>3)): bank (8*kp+n)%32 distinct -> free
// Phase B: base read ONCE per (n,k), d-loop innermost; wc stores 16B/lane,
// 8 lanes cover 128B contiguous per row. All global traffic coalesced.
// ---------------------------------------------------------------------------
__global__ __launch_bounds__(256) void combine_w(
    const float* __restrict__ bw,
    const int* __restrict__ qwq, const int* __restrict__ qwk, const int* __restrict__ qwv,
    const int* __restrict__ qzq, const int* __restrict__ qzk, const int* __restrict__ qzv,
    const float* __restrict__ scq, const float* __restrict__ sck, const float* __restrict__ scv,
    short* __restrict__ wc) {
  __shared__ int ldsq[4][8][72];
  __shared__ float zs[4][64], ss[4][64];
  const int tid = threadIdx.x;
  const int n0  = blockIdx.y * 64;
  const int kp0 = blockIdx.x * 8;   // k0 = kp0*8

  const int* qw; const int* qz; const float* sc; int Ns, nb;
  if (n0 < NQ)            { qw = qwq; qz = qzq; sc = scq; Ns = NQ;  nb = n0; }
  else if (n0 < NQ + NKV) { qw = qwk; qz = qzk; sc = sck; Ns = NKV; nb = n0 - NQ; }
  else                    { qw = qwv; qz = qzv; sc = scv; Ns = NKV; nb = n0 - NQ - NKV; }

  // zeros + scales: tid -> (d = tid>>6, n = tid&63)
  {
    int d = tid >> 6, n = tid & 63;
    int nn = nb + n;
    int z = (int)(((unsigned)qz[d * (Ns >> 3) + (nn >> 3)] >> ((nn & 7) * 4)) & 0xFu);
    zs[d][n] = (float)(z + 1);
    ss[d][n] = sc[d * Ns + nn];
  }

  // phase A: stage raw ints (coalesced along n; conflict-free LDS writes)
#pragma unroll
  for (int d = 0; d < 4; d++) {
#pragma unroll
    for (int p = 0; p < 2; p++) {
      int i  = tid + p * 256;
      int kp = i >> 6, n = i & 63;
      ldsq[d][kp][n] = qw[((size_t)d * KPACK + kp0 + kp) * Ns + nb + n];
    }
  }
  __syncthreads();

  // phase B: lane -> (kp = tid&7, n = tid>>3 + p*32); base once, d innermost
  const int kp = tid & 7;
#pragma unroll
  for (int p = 0; p < 2; p++) {
    int n = (tid >> 3) + p * 32;
    const float4* bp = (const float4*)(bw + (size_t)(n0 + n) * HIDDEN + (kp0 + kp) * 8);
    float4 b0 = bp[0], b1 = bp[1];
    float bv[8] = {b0.x, b0.y, b0.z, b0.w, b1.x, b1.y, b1.z, b1.w};
#pragma unroll
    for (int d = 0; d < 4; d++) {
      unsigned q32 = (unsigned)ldsq[d][kp][n];
      float z = zs[d][n], s = ss[d][n];
      short8v o;
#pragma unroll
      for (int j = 0; j < 8; j++)
        o[j] = f2bf(((float)((q32 >> (4 * j)) & 0xFu) - z) * s + bv[j]);
      *(short8v*)(wc + ((size_t)d * NTOT + n0 + n) * HIDDEN + (kp0 + kp) * 8) = o;
    }
  }
}

// ---------------------------------------------------------------------------
// Helpers for the pipelined GEMM
// ---------------------------------------------------------------------------
__device__ __forceinline__ void stage_tile(const short* gA0, const short* gA1,
                                           const short* gB0, const short* gB1,
                                           const short* gB2, const short* gB3,
                                           int k0, short* aDst, short* bDst) {
  load_lds16(gA0 + k0, aDst);
  load_lds16(gA1 + k0, aDst + 512);
  load_lds16(gB0 + k0, bDst);
  load_lds16(gB1 + k0, bDst + 512);
  load_lds16(gB2 + k0, bDst + 1024);
  load_lds16(gB3 + k0, bDst + 1536);
}

__device__ __forceinline__ void compute_tile(const short* Ab, const short* Bb,
                                             int wm, int wn, int mrow, int sx,
                                             floatx4 acc[4][8]) {
  bf16x8 a[4], b[8];
#pragma unroll
  for (int i = 0; i < 4; i++)
    a[i] = *(const bf16x8*)(Ab + (wm + i * 16 + mrow) * 32 + sx);
#pragma unroll
  for (int j = 0; j < 8; j++)
    b[j] = *(const bf16x8*)(Bb + (wn + j * 16 + mrow) * 32 + sx);
#pragma unroll
  for (int i = 0; i < 4; i++)
#pragma unroll
    for (int j = 0; j < 8; j++)
      acc[i][j] = __builtin_amdgcn_mfma_f32_16x16x32_bf16(a[i], b[j], acc[i][j], 0, 0, 0);
}

// ---------------------------------------------------------------------------
// Kernel 4: grouped gathered GEMM. out[tok] = xb[tok] @ Wc[d]^T
// 128x256 tile, BK=32, 4 waves each owning a 64x128 sub-tile (4x8 of
// 16x16x32 bf16 MFMA). XOR-swizzled staging keeps ds_read_b128
// conflict-free under global_load_lds's linear lane map.
//
// v2: LDS double-buffered, ONE barrier per K-step (catalog T3 "minimum
// 2-phase"). Prefetch of tile t+1 is issued BEFORE compute of tile t, so
// the vmcnt(0) drain inside the end-of-step __syncthreads lands after
// ~600 cyc of ds_read+MFMA has hidden the global-load latency. Previous
// serial stage->drain->compute exposed full L2/HBM latency on every one
// of the 128 K-steps (MfmaUtil 30%, nothing saturated = latency-bound).
// LDS 48.5 KB -> still 2 blocks/CU (97 KB < 160 KB).
// ---------------------------------------------------------------------------
#define A_BUF 4096   // shorts per A buffer (128*32)
#define B_BUF 8192   // shorts per B buffer (256*32)

__global__ __launch_bounds__(256, 2) void gemm_grouped(
    const short* __restrict__ xb, const short* __restrict__ wc,
    const int* __restrict__ token_list, const int* __restrict__ grp,
    float* __restrict__ out) {
  const int nt = grp[8];
  if ((int)blockIdx.y >= nt) return;
  const int te = grp[9 + blockIdx.y];
  const int d  = te & 3;
  const int rt = te >> 2;
  const int cnt   = grp[4 + d];
  const int start = grp[d];
  const int n0 = blockIdx.x * 256;

  __shared__ __align__(16) short As[2 * A_BUF];   // 16 KB
  __shared__ __align__(16) short Bs[2 * B_BUF];   // 32 KB
  __shared__ int toks[128];

  const int tid = threadIdx.x;
  if (tid < 128) {
    int r = rt * 128 + tid;
    if (r >= cnt) r = cnt - 1;          // clamp tail (stores guarded below)
    toks[tid] = token_list[start + r];
  }
  __syncthreads();

  const int wave = tid >> 6;
  const int lane = tid & 63;

  // staging unit u (16B) holds global (row = u>>2, seg = (u&3)^((u>>3)&3));
  // chunk offsets are multiples of 64 units -> per-lane seg swizzle fixed:
  const int sw = ((lane & 3) ^ ((lane >> 3) & 3)) * 8;  // shorts

  // A: 512 units; wave w covers u = w*128 + {0,64} + lane
  const int arow0 = wave * 32 + (lane >> 2);            // row of unit w*128+lane
  const short* gA0 = xb + (size_t)toks[arow0] * HIDDEN + sw;
  const short* gA1 = xb + (size_t)toks[arow0 + 16] * HIDDEN + sw;
  short* lA = As + (size_t)wave * 1024;                 // +lane*16B implicit

  // B: 1024 units; wave w covers u = w*256 + {0,64,128,192} + lane
  const short* wrow = wc + ((size_t)d * NTOT + n0) * HIDDEN;
  const int brow0 = wave * 64 + (lane >> 2);
  const short* gB0 = wrow + (size_t)brow0 * HIDDEN + sw;
  const short* gB1 = gB0 + (size_t)16 * HIDDEN;
  const short* gB2 = gB0 + (size_t)32 * HIDDEN;
  const short* gB3 = gB0 + (size_t)48 * HIDDEN;
  short* lB = Bs + (size_t)wave * 2048;

  const int mrow = lane & 15;
  // fragment read: (row r, kseg s) lives at unit r*4 + (s^((r>>1)&3));
  // r = mrow + mult-of-16 -> (r>>1)&3 == (mrow>>1)&3
  const int sx = (((lane >> 4) ^ ((mrow >> 1) & 3))) * 8;
  const int wm = (wave >> 1) * 64;
  const int wn = (wave & 1) * 128;

  floatx4 acc[4][8];
#pragma unroll
  for (int i = 0; i < 4; i++)
#pragma unroll
    for (int j = 0; j < 8; j++) acc[i][j] = (floatx4){0.f, 0.f, 0.f, 0.f};

  // prologue: stage K-step 0 into buffer 0
  stage_tile(gA0, gA1, gB0, gB1, gB2, gB3, 0, lA, lB);
  __syncthreads();

  // main loop, unrolled x2 so buffer selection is compile-time.
  // each iteration handles K-steps k0 (buf0) and k0+32 (buf1).
  for (int k0 = 0; k0 < HIDDEN; k0 += 64) {
    // prefetch k0+32 into buf1, then compute buf0
    stage_tile(gA0, gA1, gB0, gB1, gB2, gB3, k0 + 32, lA + A_BUF, lB + B_BUF);
    compute_tile(As, Bs, wm, wn, mrow, sx, acc);
    __syncthreads();   // drains vmcnt(0): buf1 ready; buf0 free to overwrite

    // prefetch k0+64 into buf0, then compute buf1
    if (k0 + 64 < HIDDEN)
      stage_tile(gA0, gA1, gB0, gB1, gB2, gB3, k0 + 64, lA, lB);
    compute_tile(As + A_BUF, Bs + B_BUF, wm, wn, mrow, sx, acc);
    __syncthreads();
  }

  // epilogue: C/D layout col = lane&15, row = (lane>>4)*4 + reg
  const int rbase = (lane >> 4) * 4;
  const int coll  = lane & 15;
#pragma unroll
  for (int i = 0; i < 4; i++) {
#pragma unroll
    for (int r = 0; r < 4; r++) {
      int m = wm + i * 16 + rbase + r;
      if (rt * 128 + m < cnt) {
        float* orow = out + (size_t)toks[m] * NTOT + n0 + wn + coll;
#pragma unroll
        for (int j = 0; j < 8; j++) orow[j * 16] = acc[i][j][r];
      }
    }
  }
}

// ---------------------------------------------------------------------------
extern "C" void kernel_launch(void* const* d_in, const int* in_sizes, int n_in,
                              void* d_out, int out_size, void* d_ws, size_t ws_size,
                              hipStream_t stream) {
  const float* x   = (const float*)d_in[0];
  const float* bw  = (const float*)d_in[1];
  const int*   qwq = (const int*)d_in[2];
  const int*   qwk = (const int*)d_in[3];
  const int*   qwv = (const int*)d_in[4];
  const int*   qzq = (const int*)d_in[5];
  const int*   qzk = (const int*)d_in[6];
  const int*   qzv = (const int*)d_in[7];
  const float* scq = (const float*)d_in[8];
  const float* sck = (const float*)d_in[9];
  const float* scv = (const float*)d_in[10];
  const int*   idx = (const int*)d_in[11];
  float* out = (float*)d_out;

  // workspace layout (needs ~235 MB)
  char* ws = (char*)d_ws;
  short* xb = (short*)ws;                                       // 33,554,432 B
  short* wc = (short*)(ws + (size_t)33554432);                  // 201,326,592 B
  int* token_list = (int*)(ws + (size_t)33554432 + 201326592);  // 16,384 B
  int* grp = token_list + TOKENS;                               // 256 B

  prep_tokens<<<1, 256, 0, stream>>>(idx, token_list, grp);
  cvt_x<<<(TOKENS * HIDDEN) / (256 * 8), 256, 0, stream>>>(x, xb);
  dim3 gc(HIDDEN / 64, NTOT / 64);  // (64, 96)
  combine_w<<<gc, 256, 0, stream>>>(bw, qwq, qwk, qwv, qzq, qzk, qzv, scq, sck, scv, wc);
  dim3 gg(NTOT / 256, MAXTILES);  // (24, 36)
  gemm_grouped<<<gg, 256, 0, stream>>>(xb, wc, token_list, grp, out);
}

// Round 2
// 570.266 us; speedup vs baseline: 1.0571x; 1.0571x over previous
//
#include <hip/hip_runtime.h>
#include <stdint.h>

// Problem constants (fixed by reference setup_inputs)
#define TOKENS 4096
#define HIDDEN 4096   // K
#define NQ     4096
#define NKV    1024
#define NTOT   6144   // NQ + 2*NKV
#define KPACK  512    // HIDDEN / 8
#define MAXTILES 20   // max sum_d ceil(cnt_d/256) = 16 + 4

typedef __attribute__((ext_vector_type(8))) __bf16 bf16x8;
typedef __attribute__((ext_vector_type(8))) short short8v;
typedef __attribute__((ext_vector_type(4))) float floatx4;

// fp32 -> bf16 round-to-nearest-even (finite inputs only)
__device__ __forceinline__ short f2bf(float f) {
  union { float f; unsigned u; } v; v.f = f;
  unsigned r = v.u + 0x7fffu + ((v.u >> 16) & 1u);
  return (short)(r >> 16);
}

// async global->LDS, 16B per lane; LDS dest = wave-uniform base + lane*16
__device__ __forceinline__ void load_lds16(const void* g, void* l) {
  __builtin_amdgcn_global_load_lds((__attribute__((address_space(1))) void*)(g),
                                   (__attribute__((address_space(3))) void*)(l),
                                   16, 0, 0);
}

// counted vmcnt wait: loads stay in flight across barriers (T4).
// "memory" clobber: no memory op (incl. global_load_lds) may cross it.
#define VMCNT(n) asm volatile("s_waitcnt vmcnt(" #n ")" ::: "memory")

// ---------------------------------------------------------------------------
// Kernel 1: bucket tokens by delta index + build compact tile table.
// grp[0..3]=start, grp[4..7]=count, grp[8]=n_tiles, grp[9..9+nt)=d|(rt<<2).
// Row tiles are 256 tokens (BM=256 in the GEMM).
// ---------------------------------------------------------------------------
__global__ __launch_bounds__(256) void prep_tokens(const int* __restrict__ idx,
                                                   int* __restrict__ token_list,
                                                   int* __restrict__ grp) {
  __shared__ int cnt[4], cur[4];
  const int tid = threadIdx.x;
  if (tid < 4) cnt[tid] = 0;
  __syncthreads();
  for (int t = tid; t < TOKENS; t += 256) {
    int d = idx[t];
    if ((unsigned)d < 4u) atomicAdd(&cnt[d], 1);
  }
  __syncthreads();
  if (tid == 0) {
    int s = 0, nt = 0;
    for (int d = 0; d < 4; d++) {
      cur[d] = s; grp[d] = s; grp[4 + d] = cnt[d]; s += cnt[d];
      int tiles = (cnt[d] + 255) >> 8;
      for (int rt = 0; rt < tiles; rt++) grp[9 + nt++] = d | (rt << 2);
    }
    grp[8] = nt;
  }
  __syncthreads();
  for (int t = tid; t < TOKENS; t += 256) {
    int d = idx[t];
    if ((unsigned)d < 4u) {
      int p = atomicAdd(&cur[d], 1);
      token_list[p] = t;
    }
  }
}

// ---------------------------------------------------------------------------
// Kernel 2: x fp32 -> bf16 (row-major (TOKENS, HIDDEN)); 8 elems/thread.
// ---------------------------------------------------------------------------
__global__ __launch_bounds__(256) void cvt_x(const float* __restrict__ x,
                                             short* __restrict__ xb) {
  size_t g = (size_t)blockIdx.x * 256 + threadIdx.x;
  size_t i = g * 8;
  float4 a = ((const float4*)(x + i))[0];
  float4 b = ((const float4*)(x + i))[1];
  short8v o;
  o[0] = f2bf(a.x); o[1] = f2bf(a.y); o[2] = f2bf(a.z); o[3] = f2bf(a.w);
  o[4] = f2bf(b.x); o[5] = f2bf(b.y); o[6] = f2bf(b.z); o[7] = f2bf(b.w);
  *(short8v*)(xb + i) = o;
}

// ---------------------------------------------------------------------------
// Kernel 3: Wc[d] (NTOT x HIDDEN bf16, B^T layout) = base + dequant(delta_d).
// (unchanged this round — will read its counters once GEMM stops dominating)
// ---------------------------------------------------------------------------
__global__ __launch_bounds__(256) void combine_w(
    const float* __restrict__ bw,
    const int* __restrict__ qwq, const int* __restrict__ qwk, const int* __restrict__ qwv,
    const int* __restrict__ qzq, const int* __restrict__ qzk, const int* __restrict__ qzv,
    const float* __restrict__ scq, const float* __restrict__ sck, const float* __restrict__ scv,
    short* __restrict__ wc) {
  __shared__ int ldsq[4][8][72];
  __shared__ float zs[4][64], ss[4][64];
  const int tid = threadIdx.x;
  const int n0  = blockIdx.y * 64;
  const int kp0 = blockIdx.x * 8;   // k0 = kp0*8

  const int* qw; const int* qz; const float* sc; int Ns, nb;
  if (n0 < NQ)            { qw = qwq; qz = qzq; sc = scq; Ns = NQ;  nb = n0; }
  else if (n0 < NQ + NKV) { qw = qwk; qz = qzk; sc = sck; Ns = NKV; nb = n0 - NQ; }
  else                    { qw = qwv; qz = qzv; sc = scv; Ns = NKV; nb = n0 - NQ - NKV; }

  // zeros + scales: tid -> (d = tid>>6, n = tid&63)
  {
    int d = tid >> 6, n = tid & 63;
    int nn = nb + n;
    int z = (int)(((unsigned)qz[d * (Ns >> 3) + (nn >> 3)] >> ((nn & 7) * 4)) & 0xFu);
    zs[d][n] = (float)(z + 1);
    ss[d][n] = sc[d * Ns + nn];
  }

  // phase A: stage raw ints (coalesced along n; conflict-free LDS writes)
#pragma unroll
  for (int d = 0; d < 4; d++) {
#pragma unroll
    for (int p = 0; p < 2; p++) {
      int i  = tid + p * 256;
      int kp = i >> 6, n = i & 63;
      ldsq[d][kp][n] = qw[((size_t)d * KPACK + kp0 + kp) * Ns + nb + n];
    }
  }
  __syncthreads();

  // phase B: lane -> (kp = tid&7, n = tid>>3 + p*32); base once, d innermost
  const int kp = tid & 7;
#pragma unroll
  for (int p = 0; p < 2; p++) {
    int n = (tid >> 3) + p * 32;
    const float4* bp = (const float4*)(bw + (size_t)(n0 + n) * HIDDEN + (kp0 + kp) * 8);
    float4 b0 = bp[0], b1 = bp[1];
    float bv[8] = {b0.x, b0.y, b0.z, b0.w, b1.x, b1.y, b1.z, b1.w};
#pragma unroll
    for (int d = 0; d < 4; d++) {
      unsigned q32 = (unsigned)ldsq[d][kp][n];
      float z = zs[d][n], s = ss[d][n];
      short8v o;
#pragma unroll
      for (int j = 0; j < 8; j++)
        o[j] = f2bf(((float)((q32 >> (4 * j)) & 0xFu) - z) * s + bv[j]);
      *(short8v*)(wc + ((size_t)d * NTOT + n0 + n) * HIDDEN + (kp0 + kp) * 8) = o;
    }
  }
}

// ---------------------------------------------------------------------------
// Kernel 4: grouped gathered GEMM. out[tok] = xb[tok] @ Wc[d]^T
//
// v3: 256x256 block tile, 512 threads / 8 waves (2M x 4N -> 128x64 per
// wave), BK=32, RING-4 LDS buffers (128 KB), counted vmcnt (T3+T4):
//   per K-tile t: [stage tile t+2 -> ring[(t+2)&3]] ; s_waitcnt vmcnt(8) ;
//                 raw s_barrier ; sched_barrier(0) ; 12 ds_read_b128 ;
//                 32 MFMA (setprio around clusters, T5)
// Never vmcnt(0) in the main loop -> loads stay in flight across barriers
// (the v0-v2 structure's __syncthreads drained vmcnt(0) per K-step: the
// measured ~70% stall at MfmaUtil 29%).
// Hazard proof: stage(t+2) overwrites buf last read at tile t-2, with a
// full barrier between last read and overwrite-issue (WAR); vmcnt(8)
// tolerates exactly tiles t+1,t+2 in flight, so tile t is landed for ALL
// waves after the barrier (RAW). Load latency slack = 2 K-tiles ~ 2500cy.
// XOR-swizzled staging (unit u holds row u>>2, seg (u&3)^((u>>3)&3))
// keeps ds_read_b128 conflict-free under global_load_lds's linear map.
// ---------------------------------------------------------------------------
__device__ __forceinline__ void stage_t(int t, short* aBuf, short* bBuf,
                                        const short* gA0, const short* gA1,
                                        const short* gB0, const short* gB1,
                                        int wave) {
  const int ko = t * 32;               // k offset in shorts
  short* la = aBuf + wave * 512;       // + lane*16B implicit
  short* lb = bBuf + wave * 512;
  load_lds16(gA0 + ko, la);
  load_lds16(gA1 + ko, la + 4096);
  load_lds16(gB0 + ko, lb);
  load_lds16(gB1 + ko, lb + 4096);
}

__device__ __forceinline__ void compute_tile(const short* Ab, const short* Bb,
                                             int wm, int wn, int mrow, int sx,
                                             floatx4 acc[8][4]) {
  bf16x8 bfr[4], afr[4];
#pragma unroll
  for (int j = 0; j < 4; j++)
    bfr[j] = *(const bf16x8*)(Bb + (wn * 64 + j * 16 + mrow) * 32 + sx);
#pragma unroll
  for (int i = 0; i < 4; i++)
    afr[i] = *(const bf16x8*)(Ab + (wm * 128 + i * 16 + mrow) * 32 + sx);
  __builtin_amdgcn_s_setprio(1);
#pragma unroll
  for (int i = 0; i < 4; i++)
#pragma unroll
    for (int j = 0; j < 4; j++)
      acc[i][j] = __builtin_amdgcn_mfma_f32_16x16x32_bf16(afr[i], bfr[j], acc[i][j], 0, 0, 0);
  __builtin_amdgcn_s_setprio(0);
#pragma unroll
  for (int i = 0; i < 4; i++)
    afr[i] = *(const bf16x8*)(Ab + (wm * 128 + (i + 4) * 16 + mrow) * 32 + sx);
  __builtin_amdgcn_s_setprio(1);
#pragma unroll
  for (int i = 0; i < 4; i++)
#pragma unroll
    for (int j = 0; j < 4; j++)
      acc[i + 4][j] = __builtin_amdgcn_mfma_f32_16x16x32_bf16(afr[i], bfr[j], acc[i + 4][j], 0, 0, 0);
  __builtin_amdgcn_s_setprio(0);
}

#define GSTEP(CUR, NXT, TNXT, VM)                                     \
  stage_t(TNXT, &As[NXT][0], &Bs[NXT][0], gA0, gA1, gB0, gB1, wave);  \
  VMCNT(VM);                                                          \
  __builtin_amdgcn_s_barrier();                                       \
  __builtin_amdgcn_sched_barrier(0);                                  \
  compute_tile(&As[CUR][0], &Bs[CUR][0], wm, wn, mrow, sx, acc);

#define GSTEP_NOST(CUR, VM)                                           \
  VMCNT(VM);                                                          \
  __builtin_amdgcn_s_barrier();                                       \
  __builtin_amdgcn_sched_barrier(0);                                  \
  compute_tile(&As[CUR][0], &Bs[CUR][0], wm, wn, mrow, sx, acc);

__global__ __launch_bounds__(512, 2) void gemm_grouped(
    const short* __restrict__ xb, const short* __restrict__ wc,
    const int* __restrict__ token_list, const int* __restrict__ grp,
    float* __restrict__ out) {
  const int nt = grp[8];
  if ((int)blockIdx.y >= nt) return;
  const int te = grp[9 + blockIdx.y];
  const int d  = te & 3;
  const int rt = te >> 2;
  const int cnt   = grp[4 + d];
  const int start = grp[d];
  const int n0 = blockIdx.x * 256;

  // ring-4 K-tile buffers: 4 x (A 16KB + B 16KB) = 128 KB
  __shared__ __align__(16) short As[4][8192];
  __shared__ __align__(16) short Bs[4][8192];
  __shared__ int toks[256];

  const int tid = threadIdx.x;
  if (tid < 256) {
    int r = rt * 256 + tid;
    if (r >= cnt) r = cnt - 1;          // clamp tail (stores guarded below)
    toks[tid] = token_list[start + r];
  }
  __syncthreads();

  const int wave = tid >> 6;
  const int lane = tid & 63;

  // staging unit u (16B) holds global (row = u>>2, seg = (u&3)^((u>>3)&3));
  // per-lane seg swizzle (chunk offsets are multiples of 64 units):
  const int sw = ((lane & 3) ^ ((lane >> 3) & 3)) * 8;  // shorts

  // A: 1024 units; wave w covers u = w*64 + lane (rows 0..127) and +512
  // (rows 128..255). Same split for B.
  const int arow = wave * 16 + (lane >> 2);
  const short* gA0 = xb + (size_t)toks[arow] * HIDDEN + sw;
  const short* gA1 = xb + (size_t)toks[arow + 128] * HIDDEN + sw;
  const short* wrow = wc + ((size_t)d * NTOT + n0) * HIDDEN;
  const short* gB0 = wrow + (size_t)arow * HIDDEN + sw;
  const short* gB1 = gB0 + (size_t)128 * HIDDEN;

  const int mrow = lane & 15;
  // fragment read: (row r, kseg s) lives at unit r*4 + (s^((r>>1)&3));
  // row bases are multiples of 16 -> (r>>1)&3 == (mrow>>1)&3
  const int sx = (((lane >> 4) ^ ((mrow >> 1) & 3))) * 8;
  const int wm = wave >> 2;   // 0..1  (M half)
  const int wn = wave & 3;    // 0..3  (N quarter)

  floatx4 acc[8][4];
#pragma unroll
  for (int i = 0; i < 8; i++)
#pragma unroll
    for (int j = 0; j < 4; j++) acc[i][j] = (floatx4){0.f, 0.f, 0.f, 0.f};

  // prologue: stage tiles 0,1 (8 loads in flight)
  stage_t(0, &As[0][0], &Bs[0][0], gA0, gA1, gB0, gB1, wave);
  stage_t(1, &As[1][0], &Bs[1][0], gA0, gA1, gB0, gB1, wave);

  // main loop: tiles 0..123 (stages through 125), then peel 124..127.
  for (int it = 0; it < 31; ++it) {
    const int t = it * 4;
    GSTEP(0, 2, t + 2, 8);
    GSTEP(1, 3, t + 3, 8);
    GSTEP(2, 0, t + 4, 8);
    GSTEP(3, 1, t + 5, 8);
  }
  GSTEP(0, 2, 126, 8);
  GSTEP(1, 3, 127, 8);
  GSTEP_NOST(2, 4);
  GSTEP_NOST(3, 0);

  // epilogue: C/D layout col = lane&15, row = (lane>>4)*4 + reg
  const int rbase = (lane >> 4) * 4;
  const int coll  = lane & 15;
#pragma unroll
  for (int i = 0; i < 8; i++) {
#pragma unroll
    for (int r = 0; r < 4; r++) {
      int m = wm * 128 + i * 16 + rbase + r;
      if (rt * 256 + m < cnt) {
        float* orow = out + (size_t)toks[m] * NTOT + n0 + wn * 64 + coll;
#pragma unroll
        for (int j = 0; j < 4; j++) orow[j * 16] = acc[i][j][r];
      }
    }
  }
}

// ---------------------------------------------------------------------------
extern "C" void kernel_launch(void* const* d_in, const int* in_sizes, int n_in,
                              void* d_out, int out_size, void* d_ws, size_t ws_size,
                              hipStream_t stream) {
  const float* x   = (const float*)d_in[0];
  const float* bw  = (const float*)d_in[1];
  const int*   qwq = (const int*)d_in[2];
  const int*   qwk = (const int*)d_in[3];
  const int*   qwv = (const int*)d_in[4];
  const int*   qzq = (const int*)d_in[5];
  const int*   qzk = (const int*)d_in[6];
  const int*   qzv = (const int*)d_in[7];
  const float* scq = (const float*)d_in[8];
  const float* sck = (const float*)d_in[9];
  const float* scv = (const float*)d_in[10];
  const int*   idx = (const int*)d_in[11];
  float* out = (float*)d_out;

  // workspace layout (needs ~235 MB)
  char* ws = (char*)d_ws;
  short* xb = (short*)ws;                                       // 33,554,432 B
  short* wc = (short*)(ws + (size_t)33554432);                  // 201,326,592 B
  int* token_list = (int*)(ws + (size_t)33554432 + 201326592);  // 16,384 B
  int* grp = token_list + TOKENS;                               // 256 B

  prep_tokens<<<1, 256, 0, stream>>>(idx, token_list, grp);
  cvt_x<<<(TOKENS * HIDDEN) / (256 * 8), 256, 0, stream>>>(x, xb);
  dim3 gc(HIDDEN / 64, NTOT / 64);  // (64, 96)
  combine_w<<<gc, 256, 0, stream>>>(bw, qwq, qwk, qwv, qzq, qzk, qzv, scq, sck, scv, wc);
  dim3 gg(NTOT / 256, MAXTILES);  // (24, 20)
  gemm_grouped<<<gg, 512, 0, stream>>>(xb, wc, token_list, grp, out);
}